// Round 3
// baseline (329.291 us; speedup 1.0000x reference)
//
#include <hip/hip_runtime.h>
#include <math.h>

typedef float v4f __attribute__((ext_vector_type(4)));
typedef float v2f __attribute__((ext_vector_type(2)));

// physical constants (match reference, f32)
#define RTF       (8.3144621f / 96487.0f)   // R/F
#define VOLS_     2.2e-06f                  // 0.1*VOL
#define VOLB_     1.98e-05f                 // VOL - VOLS
#define INV_TDIFF (1.0f / 7.0e6f)

#define LUT_N 4096
#define ROWS  4                              // consecutive rows per thread
// d_ws layout: [0, 32KB): lutJ2 (v2f per entry: {1/(2J0(x_i)), 1/(2J0(x_{i+1}))})
//              [32KB, 96KB): lutO4 (v4f per entry: {mlp(x_i), rtfLog(x_i), mlp(x_{i+1}), rtfLog(x_{i+1})})

__device__ __forceinline__ float asinh_pos(float x) {
    // x >= 0 here (current i in [1,3] A)
    return __logf(x + sqrtf(fmaf(x, x, 1.0f)));
}

// ---------------- LUT build helpers ----------------
__device__ __forceinline__ float jval(float x) {
    // 1/(2*J0): J0 = 1e-18 + 20000*sqrt(x*(1-x))
    float j0 = 1e-18f + 20000.0f * sqrtf(fmaxf(x * (1.0f - x), 0.0f));
    return 1.0f / (2.0f * j0);
}

__device__ __forceinline__ void mlp_log_eval(
    float x,
    const float* __restrict__ Wp0, const float* __restrict__ bp0,
    const float* __restrict__ Wp2, const float* __restrict__ bp2,
    const float* __restrict__ Wp4, const float* __restrict__ bp4,
    float* mlp_out, float* log_out)
{
    float h1[8];
#pragma unroll
    for (int j = 0; j < 8; j++)
        h1[j] = tanhf(fmaf(x, Wp0[j], bp0[j]));
    float mlp = bp4[0];
#pragma unroll
    for (int k = 0; k < 4; k++) {
        float a = bp2[k];
#pragma unroll
        for (int j = 0; j < 8; j++)
            a = fmaf(h1[j], Wp2[k * 8 + j], a);
        mlp = fmaf(tanhf(a), Wp4[k], mlp);
    }
    *mlp_out = mlp;
    // (R/F) * log(clip((1-x)/x, 1e-18, 1e18))
    float r = fminf(fmaxf((1.0f - x) / fmaxf(x, 1e-30f), 1e-18f), 1e18f);
    *log_out = RTF * logf(r);
}

// ---------------- LUT build kernel (runs every launch; 16 blocks, trivial cost) ----------------
__global__ __launch_bounds__(256) void build_lut_kernel(
    const float* __restrict__ Wp0, const float* __restrict__ bp0,
    const float* __restrict__ Wp2, const float* __restrict__ bp2,
    const float* __restrict__ Wp4, const float* __restrict__ bp4,
    v2f* __restrict__ lutJ2, v4f* __restrict__ lutO4)
{
    int idx = blockIdx.x * blockDim.x + threadIdx.x;
    if (idx >= LUT_N) return;
    const float dx = 1.0f / (float)(LUT_N - 1);
    float x0 = (float)idx * dx;
    float x1 = fminf(x0 + dx, 1.0f);

    v2f j; j.x = jval(x0); j.y = jval(x1);
    lutJ2[idx] = j;

    float m0, l0, m1, l1;
    mlp_log_eval(x0, Wp0, bp0, Wp2, bp2, Wp4, bp4, &m0, &l0);
    mlp_log_eval(x1, Wp0, bp0, Wp2, bp2, Wp4, bp4, &m1, &l1);
    v4f o; o.x = m0; o.y = l0; o.z = m1; o.w = l1;
    lutO4[idx] = o;
}

// ---------------- per-row physics ----------------
__device__ __forceinline__ void process_row(
    float Tb, float Vo, float Vsn, float Vsp,
    float qnB, float qnS, float qpB, float qpS,
    float i, float qm, float ro,
    float wn, float wbn,
    const v2f* __restrict__ lutJ2, const v4f* __restrict__ lutO4,
    float& Vout, v4f& o0, v4f& o1)
{
    // ---- getNextState ----
    float invq = __fdividef(1.0f, qm * 1000.0f);   // 1/qSMax

    float xpS = fminf(fmaxf(qpS * invq, 1e-18f), 1.0f);
    float xnS = fminf(fmaxf(qnS * invq, 1e-18f), 1.0f);

    // paired-LUT lerp for 1/(2*J0): one 8B gather per lookup
    float tn = xnS * (float)(LUT_N - 1);
    float tp = xpS * (float)(LUT_N - 1);
    int in0 = min((int)tn, LUT_N - 2);
    int ip0 = min((int)tp, LUT_N - 2);
    float fn = tn - (float)in0;
    float fp = tp - (float)ip0;
    v2f jn = lutJ2[in0];
    v2f jp = lutJ2[ip0];
    float inv2Jn = fmaf(fn, jn.y - jn.x, jn.x);
    float inv2Jp = fmaf(fp, jp.y - jp.x, jp.x);

    float qdotn = (qnB * (1.0f / VOLB_) - qnS * (1.0f / VOLS_)) * INV_TDIFF;
    float qdotp = (qpB * (1.0f / VOLB_) - qpS * (1.0f / VOLS_)) * INV_TDIFF;

    float Jn     = i * 5000.0f;             // i/SN (== i/SP)
    float VoNom  = i * ro * 10.0f;
    float coef   = RTF * Tb * 2.0f;         // R*Tb/F/ALPHA
    float VsnNom = coef * asinh_pos(Jn * inv2Jn);
    float VspNom = coef * asinh_pos(Jn * inv2Jp);

    float Vo2  = Vo  + (VoNom  - Vo ) * 0.1f;
    float Vsn2 = Vsn + (VsnNom - Vsn) * (1.0f / 90.0f);
    float Vsp2 = Vsp + (VspNom - Vsp) * (1.0f / 90.0f);
    float qnB2 = qnB - qdotn;
    float qnS2 = qnS + qdotn - i;
    float qpB2 = qpB - qdotp;
    float qpS2 = qpS + i + qdotp;

    // ---- getNextOutput (on XNew) ----
    float xp = qpS2 * invq;
    float xn = qnS2 * invq;

    float tpo = fminf(fmaxf(xp, 0.0f), 1.0f) * (float)(LUT_N - 1);
    float tno = fminf(fmaxf(xn, 0.0f), 1.0f) * (float)(LUT_N - 1);
    int ipo = min((int)tpo, LUT_N - 2);
    int ino = min((int)tno, LUT_N - 2);
    float fpo = tpo - (float)ipo;
    float fno = tno - (float)ino;
    v4f op = lutO4[ipo];          // {mlp_i, log_i, mlp_i1, log_i1}
    v4f on = lutO4[ino];
    float mlp_p = fmaf(fpo, op.z - op.x, op.x);
    float log_p = fmaf(fpo, op.w - op.y, op.y);
    float log_n = fmaf(fno, on.w - on.y, on.y);

    float Vep = 4.03f + Tb * log_p + mlp_p;
    float Ven = 0.01f + Tb * log_n + fmaf(xn, wn, wbn);
    Vout = Vep - Ven - Vo2 - Vsn2 - Vsp2;

    o0.x = Tb;   o0.y = Vo2;  o0.z = Vsn2; o0.w = Vsp2;
    o1.x = qnB2; o1.y = qnS2; o1.z = qpB2; o1.w = qpS2;
}

// ---------------- main kernel: 4 consecutive rows/thread, all-vector loads/stores ----------------
__global__ __launch_bounds__(256) void battery_cell_kernel(
    const float* __restrict__ inp,   // [B]
    const float* __restrict__ st,    // [B,8]
    const float* __restrict__ qMaxp, // [B]
    const float* __restrict__ Rop,   // [B]
    const float* __restrict__ Wn,    // [1,1]
    const float* __restrict__ bn,    // [1]
    const v2f*   __restrict__ lutJ2, // [LUT_N]
    const v4f*   __restrict__ lutO4, // [LUT_N]
    float* __restrict__ outV,        // [B]
    float* __restrict__ outX,        // [B,8]
    int B)
{
    int t = blockIdx.x * blockDim.x + threadIdx.x;
    int base = t * ROWS;
    if (base >= B) return;

    float wn = Wn[0], wbn = bn[0];

    if (base + ROWS <= B) {
        // ---- batched load front: 11 vector loads, 176B issued back-to-back ----
        v4f vi = *(const v4f*)(inp   + base);
        v4f vq = *(const v4f*)(qMaxp + base);
        v4f vr = *(const v4f*)(Rop   + base);
        v4f s[8];
        const v4f* stp = (const v4f*)st + 2 * base;
#pragma unroll
        for (int k = 0; k < 8; k++) s[k] = stp[k];

        v4f ov;
        v4f ox[8];
#pragma unroll
        for (int r = 0; r < ROWS; r++) {
            float V;
            v4f o0, o1;
            process_row(s[2 * r].x, s[2 * r].y, s[2 * r].z, s[2 * r].w,
                        s[2 * r + 1].x, s[2 * r + 1].y, s[2 * r + 1].z, s[2 * r + 1].w,
                        vi[r], vq[r], vr[r], wn, wbn, lutJ2, lutO4,
                        V, o0, o1);
            ov[r] = V;
            ox[2 * r]     = o0;
            ox[2 * r + 1] = o1;
        }

        // ---- batched store back: plain stores (L2 write-back merges lines) ----
        *(v4f*)(outV + base) = ov;
        v4f* oxp = (v4f*)outX + 2 * base;
#pragma unroll
        for (int k = 0; k < 8; k++) oxp[k] = ox[k];
    } else {
        // tail: per-row guarded scalar path
        for (int r = 0; r < ROWS; r++) {
            int b = base + r;
            if (b >= B) break;
            const v4f* stp = (const v4f*)st;
            v4f s0 = stp[2 * b];
            v4f s1 = stp[2 * b + 1];
            float V;
            v4f o0, o1;
            process_row(s0.x, s0.y, s0.z, s0.w, s1.x, s1.y, s1.z, s1.w,
                        inp[b], qMaxp[b], Rop[b], wn, wbn, lutJ2, lutO4,
                        V, o0, o1);
            outV[b] = V;
            v4f* oxp = (v4f*)outX;
            oxp[2 * b]     = o0;
            oxp[2 * b + 1] = o1;
        }
    }
}

extern "C" void kernel_launch(void* const* d_in, const int* in_sizes, int n_in,
                              void* d_out, int out_size, void* d_ws, size_t ws_size,
                              hipStream_t stream) {
    const float* inp  = (const float*)d_in[0];
    const float* st   = (const float*)d_in[1];
    const float* qMax = (const float*)d_in[2];
    const float* Ro   = (const float*)d_in[3];
    const float* Wp0  = (const float*)d_in[4];
    const float* bp0  = (const float*)d_in[5];
    const float* Wp2  = (const float*)d_in[6];
    const float* bp2  = (const float*)d_in[7];
    const float* Wp4  = (const float*)d_in[8];
    const float* bp4  = (const float*)d_in[9];
    const float* Wn   = (const float*)d_in[10];
    const float* bn   = (const float*)d_in[11];

    int B = in_sizes[0];
    float* outV = (float*)d_out;
    float* outX = (float*)d_out + B;

    v2f* lutJ2 = (v2f*)d_ws;                            // 32 KB
    v4f* lutO4 = (v4f*)((char*)d_ws + LUT_N * 8);       // 64 KB

    build_lut_kernel<<<LUT_N / 256, 256, 0, stream>>>(
        Wp0, bp0, Wp2, bp2, Wp4, bp4, lutJ2, lutO4);

    int threads_needed = (B + ROWS - 1) / ROWS;
    int grid = (threads_needed + 255) / 256;
    battery_cell_kernel<<<grid, 256, 0, stream>>>(
        inp, st, qMax, Ro, Wn, bn, lutJ2, lutO4, outV, outX, B);
}

// Round 4
// 291.963 us; speedup vs baseline: 1.1279x; 1.1279x over previous
//
#include <hip/hip_runtime.h>
#include <math.h>

typedef float v4f __attribute__((ext_vector_type(4)));
typedef float v2f __attribute__((ext_vector_type(2)));

// physical constants (match reference, f32)
#define RTF       (8.3144621f / 96487.0f)   // R/F
#define VOLS_     2.2e-06f                  // 0.1*VOL
#define VOLB_     1.98e-05f                 // VOL - VOLS
#define INV_TDIFF (1.0f / 7.0e6f)

#define LUT_N 2048
#define BLOCK 512
// d_ws layout (contiguous 48KB, staged to LDS by main kernel):
//   [0, 16KB):      lutJ2 (v2f per entry: {1/(2J0(x_i)), 1/(2J0(x_{i+1}))})
//   [16KB, 48KB):   lutO4 (v4f per entry: {mlp(x_i), rtfLog(x_i), mlp(x_{i+1}), rtfLog(x_{i+1})})

__device__ __forceinline__ float asinh_pos(float x) {
    // x >= 0 here (current i in [1,3] A)
    return __logf(x + sqrtf(fmaf(x, x, 1.0f)));
}

// ---------------- LUT build helpers ----------------
__device__ __forceinline__ float jval(float x) {
    // 1/(2*J0): J0 = 1e-18 + 20000*sqrt(x*(1-x))
    float j0 = 1e-18f + 20000.0f * sqrtf(fmaxf(x * (1.0f - x), 0.0f));
    return 1.0f / (2.0f * j0);
}

__device__ __forceinline__ void mlp_log_eval(
    float x,
    const float* __restrict__ Wp0, const float* __restrict__ bp0,
    const float* __restrict__ Wp2, const float* __restrict__ bp2,
    const float* __restrict__ Wp4, const float* __restrict__ bp4,
    float* mlp_out, float* log_out)
{
    float h1[8];
#pragma unroll
    for (int j = 0; j < 8; j++)
        h1[j] = tanhf(fmaf(x, Wp0[j], bp0[j]));
    float mlp = bp4[0];
#pragma unroll
    for (int k = 0; k < 4; k++) {
        float a = bp2[k];
#pragma unroll
        for (int j = 0; j < 8; j++)
            a = fmaf(h1[j], Wp2[k * 8 + j], a);
        mlp = fmaf(tanhf(a), Wp4[k], mlp);
    }
    *mlp_out = mlp;
    // (R/F) * log(clip((1-x)/x, 1e-18, 1e18))
    float r = fminf(fmaxf((1.0f - x) / fmaxf(x, 1e-30f), 1e-18f), 1e18f);
    *log_out = RTF * logf(r);
}

// ---------------- LUT build kernel (runs every launch; 8 blocks, trivial cost) ----------------
__global__ __launch_bounds__(256) void build_lut_kernel(
    const float* __restrict__ Wp0, const float* __restrict__ bp0,
    const float* __restrict__ Wp2, const float* __restrict__ bp2,
    const float* __restrict__ Wp4, const float* __restrict__ bp4,
    v2f* __restrict__ lutJ2, v4f* __restrict__ lutO4)
{
    int idx = blockIdx.x * blockDim.x + threadIdx.x;
    if (idx >= LUT_N) return;
    const float dx = 1.0f / (float)(LUT_N - 1);
    float x0 = (float)idx * dx;
    float x1 = fminf(x0 + dx, 1.0f);

    v2f j; j.x = jval(x0); j.y = jval(x1);
    lutJ2[idx] = j;

    float m0, l0, m1, l1;
    mlp_log_eval(x0, Wp0, bp0, Wp2, bp2, Wp4, bp4, &m0, &l0);
    mlp_log_eval(x1, Wp0, bp0, Wp2, bp2, Wp4, bp4, &m1, &l1);
    v4f o; o.x = m0; o.y = l0; o.z = m1; o.w = l1;
    lutO4[idx] = o;
}

// ---------------- main kernel: 1 row/thread, LUTs in LDS ----------------
__global__ __launch_bounds__(BLOCK) void battery_cell_kernel(
    const float* __restrict__ inp,   // [B]
    const float* __restrict__ st,    // [B,8]
    const float* __restrict__ qMaxp, // [B]
    const float* __restrict__ Rop,   // [B]
    const float* __restrict__ Wn,    // [1,1]
    const float* __restrict__ bn,    // [1]
    const float* __restrict__ lutG,  // [12288] contiguous {J2, O4}
    float* __restrict__ outV,        // [B]
    float* __restrict__ outX,        // [B,8]
    int B)
{
    // 48KB static LDS: [0,4096) floats = lutJ2, [4096,12288) = lutO4
    __shared__ float slut[12288];

    int b = blockIdx.x * BLOCK + threadIdx.x;

    // ---- issue input loads FIRST (latency hidden under staging + barrier) ----
    bool active = (b < B);
    int bc = active ? b : 0;       // clamped index; inactive lanes load row 0 harmlessly
    const v4f* st4 = (const v4f*)st;
    v4f s0 = st4[2 * bc];
    v4f s1 = st4[2 * bc + 1];
    float i  = inp[bc];
    float qm = qMaxp[bc];
    float ro = Rop[bc];
    float wn = Wn[0], wbn = bn[0];

    // ---- stage 48KB LUT into LDS: 3072 v4f, 6 per thread, unit-stride ----
    {
        const v4f* src = (const v4f*)lutG;
        v4f* dst = (v4f*)slut;
#pragma unroll
        for (int k = 0; k < 6; k++)
            dst[threadIdx.x + k * BLOCK] = src[threadIdx.x + k * BLOCK];
    }
    __syncthreads();
    const v2f* lutJ2 = (const v2f*)slut;
    const v4f* lutO4 = (const v4f*)(slut + 4096);

    if (!active) return;

    float Tb  = s0.x, Vo  = s0.y, Vsn = s0.z, Vsp = s0.w;
    float qnB = s1.x, qnS = s1.y, qpB = s1.z, qpS = s1.w;

    // ---- getNextState ----
    float invq = __fdividef(1.0f, qm * 1000.0f);   // 1/qSMax

    float xpS = fminf(fmaxf(qpS * invq, 1e-18f), 1.0f);
    float xnS = fminf(fmaxf(qnS * invq, 1e-18f), 1.0f);

    // paired-LUT lerp for 1/(2*J0): one 8B LDS read per lookup
    float tn = xnS * (float)(LUT_N - 1);
    float tp = xpS * (float)(LUT_N - 1);
    int in0 = min((int)tn, LUT_N - 2);
    int ip0 = min((int)tp, LUT_N - 2);
    float fn = tn - (float)in0;
    float fp = tp - (float)ip0;
    v2f jn = lutJ2[in0];
    v2f jp = lutJ2[ip0];
    float inv2Jn = fmaf(fn, jn.y - jn.x, jn.x);
    float inv2Jp = fmaf(fp, jp.y - jp.x, jp.x);

    float qdotn = (qnB * (1.0f / VOLB_) - qnS * (1.0f / VOLS_)) * INV_TDIFF;
    float qdotp = (qpB * (1.0f / VOLB_) - qpS * (1.0f / VOLS_)) * INV_TDIFF;

    float Jn     = i * 5000.0f;             // i/SN (== i/SP)
    float VoNom  = i * ro * 10.0f;
    float coef   = RTF * Tb * 2.0f;         // R*Tb/F/ALPHA
    float VsnNom = coef * asinh_pos(Jn * inv2Jn);
    float VspNom = coef * asinh_pos(Jn * inv2Jp);

    float Vo2  = Vo  + (VoNom  - Vo ) * 0.1f;
    float Vsn2 = Vsn + (VsnNom - Vsn) * (1.0f / 90.0f);
    float Vsp2 = Vsp + (VspNom - Vsp) * (1.0f / 90.0f);
    float qnB2 = qnB - qdotn;
    float qnS2 = qnS + qdotn - i;
    float qpB2 = qpB - qdotp;
    float qpS2 = qpS + i + qdotp;

    // ---- getNextOutput (on XNew) ----
    float xp = qpS2 * invq;
    float xn = qnS2 * invq;

    float tpo = fminf(fmaxf(xp, 0.0f), 1.0f) * (float)(LUT_N - 1);
    float tno = fminf(fmaxf(xn, 0.0f), 1.0f) * (float)(LUT_N - 1);
    int ipo = min((int)tpo, LUT_N - 2);
    int ino = min((int)tno, LUT_N - 2);
    float fpo = tpo - (float)ipo;
    float fno = tno - (float)ino;
    v4f op = lutO4[ipo];          // {mlp_i, log_i, mlp_i1, log_i1}
    v4f on = lutO4[ino];
    float mlp_p = fmaf(fpo, op.z - op.x, op.x);
    float log_p = fmaf(fpo, op.w - op.y, op.y);
    float log_n = fmaf(fno, on.w - on.y, on.y);

    float Vep = 4.03f + Tb * log_p + mlp_p;
    float Ven = 0.01f + Tb * log_n + fmaf(xn, wn, wbn);
    float V = Vep - Ven - Vo2 - Vsn2 - Vsp2;

    // ---- plain coalesced stores (L2 write-back merges full lines; R0/R3 proved ideal WRITE_SIZE) ----
    outV[b] = V;
    v4f o0; o0.x = Tb;   o0.y = Vo2;  o0.z = Vsn2; o0.w = Vsp2;
    v4f o1; o1.x = qnB2; o1.y = qnS2; o1.z = qpB2; o1.w = qpS2;
    v4f* ox4 = (v4f*)outX;
    ox4[2 * b]     = o0;
    ox4[2 * b + 1] = o1;
}

extern "C" void kernel_launch(void* const* d_in, const int* in_sizes, int n_in,
                              void* d_out, int out_size, void* d_ws, size_t ws_size,
                              hipStream_t stream) {
    const float* inp  = (const float*)d_in[0];
    const float* st   = (const float*)d_in[1];
    const float* qMax = (const float*)d_in[2];
    const float* Ro   = (const float*)d_in[3];
    const float* Wp0  = (const float*)d_in[4];
    const float* bp0  = (const float*)d_in[5];
    const float* Wp2  = (const float*)d_in[6];
    const float* bp2  = (const float*)d_in[7];
    const float* Wp4  = (const float*)d_in[8];
    const float* bp4  = (const float*)d_in[9];
    const float* Wn   = (const float*)d_in[10];
    const float* bn   = (const float*)d_in[11];

    int B = in_sizes[0];
    float* outV = (float*)d_out;
    float* outX = (float*)d_out + B;

    v2f* lutJ2 = (v2f*)d_ws;                            // 16 KB
    v4f* lutO4 = (v4f*)((char*)d_ws + LUT_N * 8);       // 32 KB

    build_lut_kernel<<<LUT_N / 256, 256, 0, stream>>>(
        Wp0, bp0, Wp2, bp2, Wp4, bp4, lutJ2, lutO4);

    int grid = (B + BLOCK - 1) / BLOCK;
    battery_cell_kernel<<<grid, BLOCK, 0, stream>>>(
        inp, st, qMax, Ro, Wn, bn, (const float*)d_ws, outV, outX, B);
}